// Round 10
// baseline (283.705 us; speedup 1.0000x reference)
//
#include <hip/hip_runtime.h>
#include <stdint.h>
#include <stddef.h>

typedef int   v4i __attribute__((ext_vector_type(4)));
typedef float v4f __attribute__((ext_vector_type(4)));

#define M_DIM 32768
#define N_DIM 1024
#define K_DIM 1024
#define BM 64            // rows per block; block owns [64][1024] of out
#define KSTEPS 16        // K=1024 / 64

// ---------------- pass 0: repack W int32 [N][K] -> fragment-linear int8 -----
// Frag id f = ((np*8 + wv)*16 + ks)*4 + j ; np=n-pass(512 cols), wv=wave,
// j = 16-col subfrag. Lane ln dword dw holds
// W[n = np*512 + wv*64 + j*16 + (ln&15)][k = ks*64 + (ln>>4)*16 + dw*4 ..+4].
__global__ __launch_bounds__(256)
void repack_w_kernel(const int* __restrict__ w32, int* __restrict__ wf)
{
    const int i  = blockIdx.x * 256 + threadIdx.x;   // dword index, < 262144
    const int f  = i >> 8;            // fragment id 0..1023
    const int r  = i & 255;
    const int ln = r >> 2;            // lane 0..63
    const int dw = r & 3;             // dword within 16B
    const int j  = f & 3;
    const int ks = (f >> 2) & 15;
    const int wv = (f >> 6) & 7;
    const int np = f >> 9;
    const int n  = np * 512 + wv * 64 + j * 16 + (ln & 15);
    const int k  = ks * 64 + (ln >> 4) * 16 + dw * 4;
    const v4i v  = *(const v4i*)&w32[(size_t)n * K_DIM + k];
    wf[i] = (v[0] & 255) | ((v[1] & 255) << 8) |
            ((v[2] & 255) << 16) | ((v[3] & 255) << 24);
}

// ---------------- fused: quantize x -> LDS, then int8 GEMM + dequant --------
// 512 threads = 8 waves; wave owns [64 rows][64 cols] per n-pass (4x4 MFMA,
// operand-swapped so n lands on reg-dim -> v4f stores).
// ILP: quant loads batched x8; B-frags register-double-buffered (b[2][4],
// static index under full unroll); first B-group issued before the barrier.
__global__ __launch_bounds__(512, 4)
void fused_kernel(const float* __restrict__ x,
                  const signed char* __restrict__ Wf,
                  const float* __restrict__ wscale,
                  const float* __restrict__ iscale_p,
                  const float* __restrict__ bias,
                  float* __restrict__ out)
{
    __shared__ signed char lA[BM * K_DIM];   // 64 KiB, swizzled col^((row&7)<<4)

    const int mrow0 = blockIdx.x * BM;
    const int t  = threadIdx.x;
    const int wv = t >> 6;
    const int ln = t & 63;
    const int lr = ln & 15;
    const int kh = (ln >> 4) * 16;

    v4i b[2][4];
    // Pre-issue B-frags for (np=0, ks=0): lands during the quant phase.
    {
        const size_t fbase = (size_t)wv * 64;          // ((0*8+wv)*16+0)*4
        #pragma unroll
        for (int j = 0; j < 4; ++j)
            b[0][j] = *(const v4i*)&Wf[(fbase + j) * 1024 + ln * 16];
    }

    // ---- phase 1: load fp32 slab (batched x8), quantize, swizzled LDS write
    {
        const float inv = 1.0f / *iscale_p;
        const int colf = (t & 255) * 4;          // int8/float column
        const int rsub = t >> 8;                 // 0..1
        for (int jb = 0; jb < 4; ++jb) {
            v4f vv[8];
            #pragma unroll
            for (int u = 0; u < 8; ++u) {
                const int row = (jb * 8 + u) * 2 + rsub;
                vv[u] = *(const v4f*)&x[(size_t)(mrow0 + row) * K_DIM + colf];
            }
            #pragma unroll
            for (int u = 0; u < 8; ++u) {
                const int row = (jb * 8 + u) * 2 + rsub;
                int r = 0;
                #pragma unroll
                for (int e = 0; e < 4; ++e) {
                    float q = rintf(vv[u][e] * inv);   // round-half-even
                    q = fminf(127.f, fmaxf(-128.f, q));
                    r |= ((int)q & 255) << (8 * e);
                }
                *(int*)&lA[row * K_DIM + (colf ^ ((row & 7) << 4))] = r;
            }
        }
    }
    __syncthreads();   // the only barrier: LDS A-tile complete

    const float is = *iscale_p;

    for (int np = 0; np < 2; ++np) {
        v4i acc[4][4] = {};
        #pragma unroll
        for (int ks = 0; ks < KSTEPS; ++ks) {
            // issue next B-group (double-buffered) before this step's MFMA
            if (ks < KSTEPS - 1) {
                const size_t fb = ((size_t)(np * 8 + wv) * 16 + (ks + 1)) * 4;
                #pragma unroll
                for (int j = 0; j < 4; ++j)
                    b[(ks + 1) & 1][j] =
                        *(const v4i*)&Wf[(fb + j) * 1024 + ln * 16];
            } else if (np == 0) {
                const size_t fb = ((size_t)8 + wv) * 16 * 4;   // (np=1, ks=0)
                #pragma unroll
                for (int j = 0; j < 4; ++j)
                    b[0][j] = *(const v4i*)&Wf[(fb + j) * 1024 + ln * 16];
            }
            v4i aF[4];
            #pragma unroll
            for (int i = 0; i < 4; ++i) {
                const int row = i * 16 + lr;
                aF[i] = *(const v4i*)&lA[row * K_DIM +
                                         ((ks * 64 + kh) ^ ((row & 7) << 4))];
            }
            // SWAPPED: first operand (W) -> reg-dim, second (x) -> lane-dim.
            #pragma unroll
            for (int i = 0; i < 4; ++i)
                #pragma unroll
                for (int j = 0; j < 4; ++j)
                    acc[i][j] = __builtin_amdgcn_mfma_i32_16x16x64_i8(
                                    b[ks & 1][j], aF[i], acc[i][j], 0, 0, 0);
        }
        // epilogue: m = mrow0 + i*16 + (ln&15); n = nb_j + (ln>>4)*4 + r.
        #pragma unroll
        for (int j = 0; j < 4; ++j) {
            const int nb = np * 512 + wv * 64 + j * 16 + ((ln >> 4) << 2);
            v4f sc4 = *(const v4f*)&wscale[nb];
            const v4f bv4 = *(const v4f*)&bias[nb];
            sc4 *= is;
            #pragma unroll
            for (int i = 0; i < 4; ++i) {
                const int m = mrow0 + i * 16 + lr;
                v4f o;
                #pragma unroll
                for (int r = 0; r < 4; ++r)
                    o[r] = (float)acc[i][j][r] * sc4[r] + bv4[r];
                *(v4f*)&out[(size_t)m * N_DIM + nb] = o;
            }
        }
    }
}

extern "C" void kernel_launch(void* const* d_in, const int* in_sizes, int n_in,
                              void* d_out, int out_size, void* d_ws, size_t ws_size,
                              hipStream_t stream)
{
    const float* x       = (const float*)d_in[0];
    const int*   w32     = (const int*)d_in[1];   // int8 weight stored as int32 [N][K]
    const float* wscale  = (const float*)d_in[2];
    const float* iscale  = (const float*)d_in[3];
    const float* bias    = (const float*)d_in[4];
    float* out           = (float*)d_out;

    signed char* wf = (signed char*)d_ws;         // 1 MiB fragment-linear W

    repack_w_kernel<<<(N_DIM * K_DIM / 4) / 256, 256, 0, stream>>>(w32, (int*)wf);

    fused_kernel<<<M_DIM / BM, 512, 0, stream>>>(x, wf, wscale, iscale, bias, out);
}

// Round 11
// 74.716 us; speedup vs baseline: 3.7971x; 3.7971x over previous
//
#include <hip/hip_runtime.h>
#include <stdint.h>
#include <stddef.h>

typedef int   v4i __attribute__((ext_vector_type(4)));
typedef float v4f __attribute__((ext_vector_type(4)));

#define M_DIM 32768
#define N_DIM 1024
#define K_DIM 1024
#define BM 64            // rows per block; block owns [64][1024] of out
#define KSTEPS 16        // K=1024 / 64

// ---------------- pass 0: repack W int32 [N][K] -> fragment-linear int8 -----
// Frag id f = ((np*8 + wv)*16 + ks)*4 + j ; np=n-pass(512 cols), wv=wave,
// j = 16-col subfrag. Lane ln dword dw holds
// W[n = np*512 + wv*64 + j*16 + (ln&15)][k = ks*64 + (ln>>4)*16 + dw*4 ..+4].
__global__ __launch_bounds__(256)
void repack_w_kernel(const int* __restrict__ w32, int* __restrict__ wf)
{
    const int i  = blockIdx.x * 256 + threadIdx.x;   // dword index, < 262144
    const int f  = i >> 8;            // fragment id 0..1023
    const int r  = i & 255;
    const int ln = r >> 2;            // lane 0..63
    const int dw = r & 3;             // dword within 16B
    const int j  = f & 3;
    const int ks = (f >> 2) & 15;
    const int wv = (f >> 6) & 7;
    const int np = f >> 9;
    const int n  = np * 512 + wv * 64 + j * 16 + (ln & 15);
    const int k  = ks * 64 + (ln >> 4) * 16 + dw * 4;
    const v4i v  = *(const v4i*)&w32[(size_t)n * K_DIM + k];
    wf[i] = (v[0] & 255) | ((v[1] & 255) << 8) |
            ((v[2] & 255) << 16) | ((v[3] & 255) << 24);
}

// ---------------- fused: quantize x -> LDS, then int8 GEMM + dequant --------
// 512 threads = 8 waves; wave owns [64 rows][64 cols] per n-pass (4x4 MFMA,
// operand-swapped so n lands on reg-dim -> v4f stores).
// Quant loads batched x8 (phase-local registers only — R10's cross-phase
// B-prefetch spilled past the 128-reg unified cap; do NOT reintroduce).
__global__ __launch_bounds__(512, 4)
void fused_kernel(const float* __restrict__ x,
                  const signed char* __restrict__ Wf,
                  const float* __restrict__ wscale,
                  const float* __restrict__ iscale_p,
                  const float* __restrict__ bias,
                  float* __restrict__ out)
{
    __shared__ signed char lA[BM * K_DIM];   // 64 KiB, swizzled col^((row&7)<<4)

    const int mrow0 = blockIdx.x * BM;
    const int t  = threadIdx.x;
    const int wv = t >> 6;
    const int ln = t & 63;
    const int lr = ln & 15;
    const int kh = (ln >> 4) * 16;

    // ---- phase 1: load fp32 slab (batched x8), quantize, swizzled LDS write
    {
        const float inv = 1.0f / *iscale_p;
        const int colf = (t & 255) * 4;          // int8/float column
        const int rsub = t >> 8;                 // 0..1
        for (int jb = 0; jb < 4; ++jb) {
            v4f vv[8];
            #pragma unroll
            for (int u = 0; u < 8; ++u) {
                const int row = (jb * 8 + u) * 2 + rsub;
                vv[u] = *(const v4f*)&x[(size_t)(mrow0 + row) * K_DIM + colf];
            }
            #pragma unroll
            for (int u = 0; u < 8; ++u) {
                const int row = (jb * 8 + u) * 2 + rsub;
                int r = 0;
                #pragma unroll
                for (int e = 0; e < 4; ++e) {
                    float q = rintf(vv[u][e] * inv);   // round-half-even
                    q = fminf(127.f, fmaxf(-128.f, q));
                    r |= ((int)q & 255) << (8 * e);
                }
                *(int*)&lA[row * K_DIM + (colf ^ ((row & 7) << 4))] = r;
            }
        }
    }
    __syncthreads();   // the only barrier: LDS A-tile complete

    const float is = *iscale_p;

    for (int np = 0; np < 2; ++np) {
        v4i acc[4][4] = {};
        #pragma unroll 4
        for (int ks = 0; ks < KSTEPS; ++ks) {
            v4i aF[4], bF[4];
            #pragma unroll
            for (int i = 0; i < 4; ++i) {
                const int row = i * 16 + lr;
                aF[i] = *(const v4i*)&lA[row * K_DIM +
                                         ((ks * 64 + kh) ^ ((row & 7) << 4))];
            }
            const size_t fbase = ((size_t)(np * 8 + wv) * 16 + ks) * 4;
            #pragma unroll
            for (int j = 0; j < 4; ++j)
                bF[j] = *(const v4i*)&Wf[(fbase + j) * 1024 + ln * 16];
            // SWAPPED: first operand (W) -> reg-dim, second (x) -> lane-dim.
            #pragma unroll
            for (int i = 0; i < 4; ++i)
                #pragma unroll
                for (int j = 0; j < 4; ++j)
                    acc[i][j] = __builtin_amdgcn_mfma_i32_16x16x64_i8(
                                    bF[j], aF[i], acc[i][j], 0, 0, 0);
        }
        // epilogue: m = mrow0 + i*16 + (ln&15); n = nb_j + (ln>>4)*4 + r.
        #pragma unroll
        for (int j = 0; j < 4; ++j) {
            const int nb = np * 512 + wv * 64 + j * 16 + ((ln >> 4) << 2);
            v4f sc4 = *(const v4f*)&wscale[nb];
            const v4f bv4 = *(const v4f*)&bias[nb];
            sc4 *= is;
            #pragma unroll
            for (int i = 0; i < 4; ++i) {
                const int m = mrow0 + i * 16 + lr;
                v4f o;
                #pragma unroll
                for (int r = 0; r < 4; ++r)
                    o[r] = (float)acc[i][j][r] * sc4[r] + bv4[r];
                *(v4f*)&out[(size_t)m * N_DIM + nb] = o;
            }
        }
    }
}

extern "C" void kernel_launch(void* const* d_in, const int* in_sizes, int n_in,
                              void* d_out, int out_size, void* d_ws, size_t ws_size,
                              hipStream_t stream)
{
    const float* x       = (const float*)d_in[0];
    const int*   w32     = (const int*)d_in[1];   // int8 weight stored as int32 [N][K]
    const float* wscale  = (const float*)d_in[2];
    const float* iscale  = (const float*)d_in[3];
    const float* bias    = (const float*)d_in[4];
    float* out           = (float*)d_out;

    signed char* wf = (signed char*)d_ws;         // 1 MiB fragment-linear W

    repack_w_kernel<<<(N_DIM * K_DIM / 4) / 256, 256, 0, stream>>>(w32, (int*)wf);

    fused_kernel<<<M_DIM / BM, 512, 0, stream>>>(x, wf, wscale, iscale, bias, out);
}

// Round 12
// 71.084 us; speedup vs baseline: 3.9912x; 1.0511x over previous
//
#include <hip/hip_runtime.h>
#include <stdint.h>
#include <stddef.h>

typedef int   v2i __attribute__((ext_vector_type(2)));
typedef int   v4i __attribute__((ext_vector_type(4)));
typedef float v4f __attribute__((ext_vector_type(4)));

#define M_DIM 32768
#define N_DIM 1024
#define K_DIM 1024
#define BM 64            // rows per block; block owns [64][1024] of out
#define KSTEPS 16        // K=1024 / 64

// LDS swizzle: physical_col = col ^ S(row).
// S = ((row&7)<<4) ^ ((row&1)<<6): bits 4-6 permute 16B chunks (aF-read
// conflict-free) AND bit6 alternates halves by row parity so the slice
// ds_write beats (4 rows/beat) cover all 32 banks (2 dwords/bank = free).
__device__ __forceinline__ int swzS(int row) {
    return ((row & 7) << 4) ^ ((row & 1) << 6);
}

// ---------------- pass 0: repack W int32 [N][K] -> fragment-linear int8 -----
// Frag id f = ((p*8 + wv)*16 + ks)*2 + j ; p = n-pass (256 cols), wv = wave,
// j = 16-col subfrag. Lane ln dword dw holds
// W[n = p*256 + wv*32 + j*16 + (ln&15)][k = ks*64 + (ln>>4)*16 + dw*4 ..+4].
__global__ __launch_bounds__(256)
void repack_w_kernel(const int* __restrict__ w32, int* __restrict__ wf)
{
    const int i  = blockIdx.x * 256 + threadIdx.x;   // dword index, < 262144
    const int f  = i >> 8;            // fragment id 0..1023
    const int r  = i & 255;
    const int ln = r >> 2;            // lane 0..63
    const int dw = r & 3;             // dword within 16B
    const int j  = f & 1;
    const int ks = (f >> 1) & 15;
    const int wv = (f >> 5) & 7;
    const int p  = f >> 8;
    const int n  = p * 256 + wv * 32 + j * 16 + (ln & 15);
    const int k  = ks * 64 + (ln >> 4) * 16 + dw * 4;
    const v4i v  = *(const v4i*)&w32[(size_t)n * K_DIM + k];
    wf[i] = (v[0] & 255) | ((v[1] & 255) << 8) |
            ((v[2] & 255) << 16) | ((v[3] & 255) << 24);
}

// ---------------- fused: K-sliced quant/GEMM pipeline + dequant -------------
// 512 threads = 8 waves. Pass 0 (cols 0-255) pipelines: per kstep, x-loads
// for slice ks+1 are issued before MFMA(ks) and packed/written after; one
// __syncthreads per kstep. Passes 1-3 are pure GEMM (A resident, no barriers).
// Per-wave tile per pass: [64m][32n] = 4x2 of 16x16x64 i8 MFMA (32 acc regs).
// Operand-swapped mfma(W, A): n on reg-dim -> v4f contiguous stores.
__global__ __launch_bounds__(512, 4)
void fused_kernel(const float* __restrict__ x,
                  const signed char* __restrict__ Wf,
                  const float* __restrict__ wscale,
                  const float* __restrict__ iscale_p,
                  const float* __restrict__ bias,
                  float* __restrict__ out)
{
    __shared__ signed char lA[BM * K_DIM];   // 64 KiB, swizzled col^S(row)

    const int mrow0 = blockIdx.x * BM;
    const int t  = threadIdx.x;
    const int wv = t >> 6;
    const int ln = t & 63;
    const int lr = ln & 15;
    const int kh = (ln >> 4) * 16;
    const float inv = 1.0f / *iscale_p;
    const float is  = *iscale_p;

    // quant-producer indexing: thread packs 8 cols of one row per slice
    const int qrow = t >> 3;              // 0..63
    const int qc   = (t & 7) * 8;         // float/byte offset within 64-slice
    const float* xrow = &x[(size_t)(mrow0 + qrow) * K_DIM];
    signed char* lArow = &lA[qrow * K_DIM];
    const int qs = swzS(qrow);

    #define PACK8(A_, B_, PR_)                                              \
        do {                                                                 \
            int lo_ = 0, hi_ = 0;                                            \
            _Pragma("unroll")                                                \
            for (int e_ = 0; e_ < 4; ++e_) {                                 \
                float qa_ = rintf((A_)[e_] * inv);                           \
                qa_ = fminf(127.f, fmaxf(-128.f, qa_));                      \
                lo_ |= ((int)qa_ & 255) << (8 * e_);                         \
                float qb_ = rintf((B_)[e_] * inv);                           \
                qb_ = fminf(127.f, fmaxf(-128.f, qb_));                      \
                hi_ |= ((int)qb_ & 255) << (8 * e_);                         \
            }                                                                \
            (PR_)[0] = lo_; (PR_)[1] = hi_;                                  \
        } while (0)

    // prologue: quantize slice 0
    {
        const v4f a = *(const v4f*)&xrow[qc];
        const v4f b = *(const v4f*)&xrow[qc + 4];
        v2i pr;
        PACK8(a, b, pr);
        *(v2i*)&lArow[qc ^ qs] = pr;
    }
    __syncthreads();

    // ---- pass 0: pipelined (quant slices 1..15 hide under MFMA) ----
    {
        v4i acc[4][2] = {};
        for (int ks = 0; ks < KSTEPS; ++ks) {
            const bool pf = (ks + 1 < KSTEPS);
            v4f xa, xb;
            if (pf) {                         // issue early: hides under MFMA
                xa = *(const v4f*)&xrow[(ks + 1) * 64 + qc];
                xb = *(const v4f*)&xrow[(ks + 1) * 64 + qc + 4];
            }
            v4i bF[2];
            const size_t fb = ((size_t)wv * 16 + ks) * 2;   // p = 0
            bF[0] = *(const v4i*)&Wf[fb * 1024 + ln * 16];
            bF[1] = *(const v4i*)&Wf[(fb + 1) * 1024 + ln * 16];
            v4i aF[4];
            #pragma unroll
            for (int i = 0; i < 4; ++i) {
                const int row = i * 16 + lr;
                aF[i] = *(const v4i*)&lA[row * K_DIM +
                                         ((ks * 64 + kh) ^ swzS(row))];
            }
            #pragma unroll
            for (int i = 0; i < 4; ++i)
                #pragma unroll
                for (int j = 0; j < 2; ++j)
                    acc[i][j] = __builtin_amdgcn_mfma_i32_16x16x64_i8(
                                    bF[j], aF[i], acc[i][j], 0, 0, 0);
            if (pf) {
                v2i pr;
                PACK8(xa, xb, pr);
                *(v2i*)&lArow[(((ks + 1) * 64) + qc) ^ qs] = pr;
                __syncthreads();              // slice ks+1 visible block-wide
            }
        }
        // epilogue p=0: m = mrow0+i*16+lr; n = nb+(ln>>4)*4+r
        #pragma unroll
        for (int j = 0; j < 2; ++j) {
            const int nb = wv * 32 + j * 16 + ((ln >> 4) << 2);
            v4f sc4 = *(const v4f*)&wscale[nb];
            const v4f bv4 = *(const v4f*)&bias[nb];
            sc4 *= is;
            #pragma unroll
            for (int i = 0; i < 4; ++i) {
                const int m = mrow0 + i * 16 + lr;
                v4f o;
                #pragma unroll
                for (int r = 0; r < 4; ++r)
                    o[r] = (float)acc[i][j][r] * sc4[r] + bv4[r];
                *(v4f*)&out[(size_t)m * N_DIM + nb] = o;
            }
        }
    }

    // ---- passes 1-3: pure GEMM, no barriers (compiler pipelines freely) ----
    for (int p = 1; p < 4; ++p) {
        v4i acc[4][2] = {};
        #pragma unroll 4
        for (int ks = 0; ks < KSTEPS; ++ks) {
            v4i bF[2];
            const size_t fb = ((size_t)(p * 8 + wv) * 16 + ks) * 2;
            bF[0] = *(const v4i*)&Wf[fb * 1024 + ln * 16];
            bF[1] = *(const v4i*)&Wf[(fb + 1) * 1024 + ln * 16];
            v4i aF[4];
            #pragma unroll
            for (int i = 0; i < 4; ++i) {
                const int row = i * 16 + lr;
                aF[i] = *(const v4i*)&lA[row * K_DIM +
                                         ((ks * 64 + kh) ^ swzS(row))];
            }
            #pragma unroll
            for (int i = 0; i < 4; ++i)
                #pragma unroll
                for (int j = 0; j < 2; ++j)
                    acc[i][j] = __builtin_amdgcn_mfma_i32_16x16x64_i8(
                                    bF[j], aF[i], acc[i][j], 0, 0, 0);
        }
        #pragma unroll
        for (int j = 0; j < 2; ++j) {
            const int nb = p * 256 + wv * 32 + j * 16 + ((ln >> 4) << 2);
            v4f sc4 = *(const v4f*)&wscale[nb];
            const v4f bv4 = *(const v4f*)&bias[nb];
            sc4 *= is;
            #pragma unroll
            for (int i = 0; i < 4; ++i) {
                const int m = mrow0 + i * 16 + lr;
                v4f o;
                #pragma unroll
                for (int r = 0; r < 4; ++r)
                    o[r] = (float)acc[i][j][r] * sc4[r] + bv4[r];
                *(v4f*)&out[(size_t)m * N_DIM + nb] = o;
            }
        }
    }
    #undef PACK8
}

extern "C" void kernel_launch(void* const* d_in, const int* in_sizes, int n_in,
                              void* d_out, int out_size, void* d_ws, size_t ws_size,
                              hipStream_t stream)
{
    const float* x       = (const float*)d_in[0];
    const int*   w32     = (const int*)d_in[1];   // int8 weight stored as int32 [N][K]
    const float* wscale  = (const float*)d_in[2];
    const float* iscale  = (const float*)d_in[3];
    const float* bias    = (const float*)d_in[4];
    float* out           = (float*)d_out;

    signed char* wf = (signed char*)d_ws;         // 1 MiB fragment-linear W

    repack_w_kernel<<<(N_DIM * K_DIM / 4) / 256, 256, 0, stream>>>(w32, (int*)wf);

    fused_kernel<<<M_DIM / BM, 512, 0, stream>>>(x, wf, wscale, iscale, bias, out);
}